// Round 18
// baseline (164.449 us; speedup 1.0000x reference)
//
#include <hip/hip_runtime.h>

#define HH 512
#define WW 512
#define HW (512*512)
#define NB 8
#define ND 16
#define TW 64            // tile width (output)
#define TH 32            // tile height (output)
#define VR 42            // v-sum rows = TH+10
#define PTW 172          // words/row: 84 cols x {F,P} + 4 pad; 172/4=43 quads (odd)
                         // -> row-lane b128 across rows is bank-quad bijective

__device__ __forceinline__ int reflect(int v) {
    if (v < 0) v = -v;
    if (v >= HH) v = 2*HH - 2 - v;
    return v;
}

// ---------------- Prepass: {mean_I, 1/(var_I+eps)} interleaved float2 ----------------
__global__ __launch_bounds__(256) void img_stats(const float* __restrict__ img,
                                                 float2* __restrict__ miv) {
    const int VRs = 42, PTs = 86, THs = 32, TWs = 64;
    __shared__ __align__(16) float hBuf[2*VRs*PTs + 20];
    float* hF = hBuf;
    float* hP = hBuf + VRs*PTs + 20;

    int blk  = blockIdx.x;
    int tile = blk & 127;
    int b    = blk >> 7;
    int ty0  = (tile >> 3) * THs;
    int tx0  = (tile & 7)  * TWs;

    const float inv121 = 1.0f/121.0f;
    const float* ib = img + (size_t)b*HW;
    const int t = threadIdx.x;

    if (t < 252) {
        int seg = t / 84, col = t - seg*84;
        int gx = reflect(tx0 - 10 + col);
        const float* icol = ib + gx;
        int vr0 = seg*14;
        float rv[11], rq[11];
        float sv = 0.f, sq = 0.f;
        #pragma unroll
        for (int j = 0; j < 10; ++j) {
            int gy = reflect(ty0 - 10 + vr0 + j);
            float v = icol[gy*WW], q = v*v;
            rv[j] = v; rq[j] = q; sv += v; sq += q;
        }
        #pragma unroll
        for (int k = 0; k < 14; ++k) {
            int vr = vr0 + k;
            int gy = reflect(ty0 + vr);
            float v = icol[gy*WW], q = v*v;
            sv += v; sq += q;
            hF[vr*PTs + col] = sv;
            hP[vr*PTs + col] = sq;
            sv -= rv[k%11]; sq -= rq[k%11];
            rv[(k+10)%11] = v; rq[(k+10)%11] = q;
        }
    }
    __syncthreads();

    if (t < 168) {
        int arr = t & 1;
        int j2  = t >> 1;
        int seg = (j2 >= 42) ? 1 : 0;
        int vr  = j2 - seg*42;
        int xb = seg ? 38 : 0;
        int nout = seg ? 18 : 19;
        float* rA = (arr ? hP : hF) + vr*PTs;
        float2 ring[5];
        float T = 0.f;
        #pragma unroll
        for (int j = 0; j < 5; ++j) {
            float2 v = *(float2*)(rA + xb + 2*j);
            ring[j] = v; T += v.x + v.y;
        }
        #pragma unroll
        for (int k2 = 0; k2 < 19; ++k2) {
            if (k2 < nout) {
                int hc = xb + 2*k2;
                float2 p = *(float2*)(rA + hc + 10);
                float2 q = ring[k2 % 5];
                float O0 = T + p.x;
                float O1 = O0 + p.y - q.x;
                T = O1 - q.y;
                ring[k2 % 5] = p;
                float2 o; o.x = O0*inv121; o.y = O1*inv121;
                *(float2*)(rA + hc + 10*seg) = o;
            }
        }
    }
    __syncthreads();

    float2* mb = miv + (size_t)b*HW;
    for (int i = t; i < THs*TWs; i += 256) {
        int y = i >> 6, x = i & 63;
        int vr = y + 5, hc = x + 5;
        int slot = hc + ((hc >= 38) ? 10 : 0);
        float mI  = hF[vr*PTs + slot];
        float mII = hP[vr*PTs + slot];
        float var = mII - mI*mI;
        float2 o; o.x = mI; o.y = 1.0f / (var + 1e-8f);
        mb[(ty0 + y)*WW + tx0 + x] = o;
    }
}

// ---------------- Main fused kernel: TWO channels, one 64x32 tile, 512 thr ------------
// Two interleaved buffers S0/S1 [42][172w] (one per channel), 57.8 KB -> 2 blocks/CU.
// Every chain phase carries both channels per thread (ILP-2) plus prefetch-2.
// Maps (units = 2 cols = one float4 {F,P,F,P}):
//   after B : su(u) = u + 5*(u>=19)     (u in 0..36)
//   after C : prow(y) = y + 10*(y>=16)  (y in 0..31)
//   after D : unit ub+k+10*seg -> {0..15, 26..41}
// All in-place proofs are R8/R16's (identical column/row arithmetic per channel).
__global__ __launch_bounds__(512) void guided_main(const float* __restrict__ feat,
                                                   const float* __restrict__ img,
                                                   const float2* __restrict__ miv,
                                                   float* __restrict__ out) {
    __shared__ __align__(16) float S[2*VR*PTW];
    float* S0 = S;
    float* S1 = S + VR*PTW;

    int blk  = blockIdx.x;
    int tile = blk & 127;        // 8 col-tiles x 16 row-tiles
    int cp   = blk >> 7;         // 0..63 : (batch, channel-pair)
    int b    = cp >> 3;
    int bd0  = b*ND + (cp & 7)*2;
    int ty0  = (tile >> 3) * TH;
    int tx0  = (tile & 7)  * TW;

    const float inv121 = 1.0f/121.0f;
    const float* fb0  = feat + (size_t)bd0*HW;
    const float* fb1  = fb0 + HW;
    const float* ib   = img  + (size_t)b*HW;
    const float2* mivb = miv + (size_t)b*HW;
    const int t = threadIdx.x;

    // ---- Phase A: vertical raw 11-sums, both channels; img loaded once ----
    // 84 cols x 3 row-segs (14 outputs) = 252 threads.
    if (t < 252) {
        int seg = t / 84, col = t - seg*84;
        int gx = reflect(tx0 - 10 + col);
        const float* f0c = fb0 + gx;
        const float* f1c = fb1 + gx;
        const float* ic  = ib + gx;
        int vr0 = seg*14;
        float rf0[11], rp0[11], rf1[11], rp1[11];
        float sf0=0.f, sp0=0.f, sf1=0.f, sp1=0.f;
        #pragma unroll
        for (int j = 0; j < 10; ++j) {
            int gy = reflect(ty0 - 10 + vr0 + j);
            float im = ic[gy*WW];
            float f0 = f0c[gy*WW], f1 = f1c[gy*WW];
            float p0 = f0*im, p1 = f1*im;
            rf0[j]=f0; rp0[j]=p0; rf1[j]=f1; rp1[j]=p1;
            sf0+=f0; sp0+=p0; sf1+=f1; sp1+=p1;
        }
        #pragma unroll
        for (int k = 0; k < 14; ++k) {
            int vr = vr0 + k;
            int gy = reflect(ty0 + vr);
            float im = ic[gy*WW];
            float f0 = f0c[gy*WW], f1 = f1c[gy*WW];
            float p0 = f0*im, p1 = f1*im;
            sf0+=f0; sp0+=p0; sf1+=f1; sp1+=p1;
            float2 s0v; s0v.x=sf0; s0v.y=sp0;
            float2 s1v; s1v.x=sf1; s1v.y=sp1;
            *(float2*)(S0 + vr*PTW + 2*col) = s0v;
            *(float2*)(S1 + vr*PTW + 2*col) = s1v;
            sf0-=rf0[k%11]; sp0-=rp0[k%11]; sf1-=rf1[k%11]; sp1-=rp1[k%11];
            rf0[(k+10)%11]=f0; rp0[(k+10)%11]=p0;
            rf1[(k+10)%11]=f1; rp1[(k+10)%11]=p1;
        }
    }
    __syncthreads();

    // ---- Phase B: horizontal 11-sums -> {mp,cip}; both channels; prefetch-2 ----
    // 42 rows x 2 col-segs = 84 threads. seg0 reads units 0..23 writes 0..18;
    // seg1 reads 19..41 writes 24..41 (read-first same unit). Prefetch trails
    // its overwrite by >=2 iters (R16 proof).
    if (t < 84) {
        int seg = (t >= 42) ? 1 : 0;
        int vr  = t - seg*42;
        float* r0 = S0 + vr*PTW;
        float* r1 = S1 + vr*PTW;
        int xbu = seg*19;
        int nout = seg ? 18 : 19;
        float4 rg0[5], rg1[5];
        float TF0=0.f, TP0=0.f, TF1=0.f, TP1=0.f;
        #pragma unroll
        for (int j = 0; j < 5; ++j) {
            float4 v0 = *(float4*)(r0 + 4*(xbu + j));
            float4 v1 = *(float4*)(r1 + 4*(xbu + j));
            rg0[j] = v0; TF0 += v0.x + v0.z; TP0 += v0.y + v0.w;
            rg1[j] = v1; TF1 += v1.x + v1.z; TP1 += v1.y + v1.w;
        }
        float4 pr0[2], pr1[2];
        #pragma unroll
        for (int j = 0; j < 2; ++j) {
            pr0[j] = *(float4*)(r0 + 4*(xbu + 5 + j));
            pr1[j] = *(float4*)(r1 + 4*(xbu + 5 + j));
        }
        #pragma unroll
        for (int k = 0; k < 19; ++k) {
            if (k < nout) {
                float4 p0 = pr0[k & 1];
                float4 p1 = pr1[k & 1];
                int nk = k + 2;
                if (nk < nout) {
                    pr0[k & 1] = *(float4*)(r0 + 4*(xbu + 5 + nk));
                    pr1[k & 1] = *(float4*)(r1 + 4*(xbu + 5 + nk));
                }
                float4 q0 = rg0[k % 5];
                float4 q1 = rg1[k % 5];
                float O0f = TF0 + p0.x;
                float O1f = O0f + p0.z - q0.x;
                TF0 = O1f - q0.z;
                float O0p = TP0 + p0.y;
                float O1p = O0p + p0.w - q0.y;
                TP0 = O1p - q0.w;
                rg0[k % 5] = p0;
                float4 o0;
                o0.x = O0f*inv121; o0.y = O0p*inv121;
                o0.z = O1f*inv121; o0.w = O1p*inv121;
                *(float4*)(r0 + 4*(k + xbu + 5*seg)) = o0;
                float G0f = TF1 + p1.x;
                float G1f = G0f + p1.z - q1.x;
                TF1 = G1f - q1.z;
                float G0p = TP1 + p1.y;
                float G1p = G0p + p1.w - q1.y;
                TP1 = G1p - q1.w;
                rg1[k % 5] = p1;
                float4 o1;
                o1.x = G0f*inv121; o1.y = G0p*inv121;
                o1.z = G1f*inv121; o1.w = G1p*inv121;
                *(float4*)(r1 + 4*(k + xbu + 5*seg)) = o1;
            }
        }
    }
    __syncthreads();

    // ---- Phase B2: a,b elementwise; both channels share miv; next-job prefetch ----
    {
        const int NJ = VR*37;   // 1554 jobs, each = one unit of BOTH channels
        int i = t;
        float *c0 = S0, *c1 = S1;
        float4 m0 = {}, m1 = {};
        float2 g0 = {}, g1 = {};
        if (i < NJ) {
            int y = i / 37, u = i - y*37;
            int su = u + ((u >= 19) ? 5 : 0);
            c0 = S0 + y*PTW + 4*su;
            c1 = S1 + y*PTW + 4*su;
            m0 = *(float4*)c0;
            m1 = *(float4*)c1;
            int gy = reflect(ty0 - 5 + y);
            const float2* mrow = mivb + gy*WW;
            int gx0 = tx0 - 5 + 2*u;
            g0 = mrow[reflect(gx0)];
            g1 = mrow[reflect(gx0+1)];
        }
        while (i < NJ) {
            int inext = i + 512;
            float *c0n = c0, *c1n = c1;
            float4 m0n = {}, m1n = {};
            float2 g0n = {}, g1n = {};
            if (inext < NJ) {
                int yn = inext / 37, un = inext - yn*37;
                int sun = un + ((un >= 19) ? 5 : 0);
                c0n = S0 + yn*PTW + 4*sun;
                c1n = S1 + yn*PTW + 4*sun;
                m0n = *(float4*)c0n;
                m1n = *(float4*)c1n;
                int gyn = reflect(ty0 - 5 + yn);
                const float2* mrown = mivb + gyn*WW;
                int gx0n = tx0 - 5 + 2*un;
                g0n = mrown[reflect(gx0n)];
                g1n = mrown[reflect(gx0n+1)];
            }
            {
                float a0 = (m0.y - g0.x*m0.x) * g0.y;
                float b0 = m0.x - a0*g0.x;
                float a1 = (m0.w - g1.x*m0.z) * g1.y;
                float b1 = m0.z - a1*g1.x;
                float4 o; o.x = a0; o.y = b0; o.z = a1; o.w = b1;
                *(float4*)c0 = o;
            }
            {
                float a0 = (m1.y - g0.x*m1.x) * g0.y;
                float b0 = m1.x - a0*g0.x;
                float a1 = (m1.w - g1.x*m1.z) * g1.y;
                float b1 = m1.z - a1*g1.x;
                float4 o; o.x = a0; o.y = b0; o.z = a1; o.w = b1;
                *(float4*)c1 = o;
            }
            i = inext; c0 = c0n; c1 = c1n; m0 = m0n; m1 = m1n; g0 = g0n; g1 = g1n;
        }
    }
    __syncthreads();

    // ---- Phase C: vertical 11-sums of {a,b}; both channels; prefetch-2 ----
    // 74 cols x 2 row-segs = 148 threads. seg0 reads rows 0..25 writes 0..15;
    // seg1 reads 16..41 writes 26..41 (read-first same row). Prefetch rows are
    // written >=2 iters after their read (R16-style proof at TH=32).
    if (t < 148) {
        int seg = (t >= 74) ? 1 : 0;
        int c   = t - seg*74;
        int sw  = 2*(c + ((c >= 38) ? 10 : 0));
        int y0  = seg*16;
        float2 r0[11], r1[11];
        float sa0=0.f, sb0=0.f, sa1=0.f, sb1=0.f;
        #pragma unroll
        for (int j = 0; j < 10; ++j) {
            float2 v0 = *(float2*)(S0 + (y0+j)*PTW + sw);
            float2 v1 = *(float2*)(S1 + (y0+j)*PTW + sw);
            r0[j] = v0; sa0 += v0.x; sb0 += v0.y;
            r1[j] = v1; sa1 += v1.x; sb1 += v1.y;
        }
        float2 p0[2], p1[2];
        #pragma unroll
        for (int j = 0; j < 2; ++j) {
            p0[j] = *(float2*)(S0 + (y0+10+j)*PTW + sw);
            p1[j] = *(float2*)(S1 + (y0+10+j)*PTW + sw);
        }
        #pragma unroll
        for (int k = 0; k < 16; ++k) {
            float2 v0 = p0[k & 1];
            float2 v1 = p1[k & 1];
            if (k + 2 < 16) {
                p0[k & 1] = *(float2*)(S0 + (y0+12+k)*PTW + sw);
                p1[k & 1] = *(float2*)(S1 + (y0+12+k)*PTW + sw);
            }
            sa0 += v0.x; sb0 += v0.y;
            sa1 += v1.x; sb1 += v1.y;
            int wrow = y0 + k + 10*seg;
            float2 o0; o0.x = sa0; o0.y = sb0;
            float2 o1; o1.x = sa1; o1.y = sb1;
            *(float2*)(S0 + wrow*PTW + sw) = o0;
            *(float2*)(S1 + wrow*PTW + sw) = o1;
            sa0 -= r0[k%11].x; sb0 -= r0[k%11].y;
            sa1 -= r1[k%11].x; sb1 -= r1[k%11].y;
            r0[(k+10)%11] = v0;
            r1[(k+10)%11] = v1;
        }
    }
    __syncthreads();

    // ---- Phase D: horizontal 11-sums of {sa,sb}; both channels; prefetch-2 ----
    // 32 rows x 2 col-segs = 64 threads. seg0 reads su{0..18,24,25} writes units
    // 0..15; seg1 reads su{16..18,24..41} writes 26..41 (R16 proof).
    if (t < 64) {
        int seg = t >> 5, row = t & 31;
        int prow = row + ((row >= 16) ? 10 : 0);
        float* w0 = S0 + prow*PTW;
        float* w1 = S1 + prow*PTW;
        int ub = seg*16;
        float4 rg0[5], rg1[5];
        float TA0=0.f, TB0=0.f, TA1=0.f, TB1=0.f;
        #pragma unroll
        for (int j = 0; j < 5; ++j) {
            int u = ub + j; int su = u + ((u >= 19) ? 5 : 0);
            float4 v0 = *(float4*)(w0 + 4*su);
            float4 v1 = *(float4*)(w1 + 4*su);
            rg0[j] = v0; TA0 += v0.x + v0.z; TB0 += v0.y + v0.w;
            rg1[j] = v1; TA1 += v1.x + v1.z; TB1 += v1.y + v1.w;
        }
        float4 pr0[2], pr1[2];
        #pragma unroll
        for (int j = 0; j < 2; ++j) {
            int u = ub + 5 + j; int su = u + ((u >= 19) ? 5 : 0);
            pr0[j] = *(float4*)(w0 + 4*su);
            pr1[j] = *(float4*)(w1 + 4*su);
        }
        #pragma unroll
        for (int k = 0; k < 16; ++k) {
            float4 p0 = pr0[k & 1];
            float4 p1 = pr1[k & 1];
            if (k + 2 < 16) {
                int u = ub + 7 + k; int su = u + ((u >= 19) ? 5 : 0);
                pr0[k & 1] = *(float4*)(w0 + 4*su);
                pr1[k & 1] = *(float4*)(w1 + 4*su);
            }
            float4 q0 = rg0[k % 5];
            float4 q1 = rg1[k % 5];
            float A0 = TA0 + p0.x;
            float A1 = A0 + p0.z - q0.x;
            TA0 = A1 - q0.z;
            float B0 = TB0 + p0.y;
            float B1 = B0 + p0.w - q0.y;
            TB0 = B1 - q0.w;
            rg0[k % 5] = p0;
            float4 o0; o0.x = A0; o0.y = B0; o0.z = A1; o0.w = B1;
            *(float4*)(w0 + 4*(ub + k) + 40*seg) = o0;
            float C0 = TA1 + p1.x;
            float C1 = C0 + p1.z - q1.x;
            TA1 = C1 - q1.z;
            float D0 = TB1 + p1.y;
            float D1 = D0 + p1.w - q1.y;
            TB1 = D1 - q1.w;
            rg1[k % 5] = p1;
            float4 o1; o1.x = C0; o1.y = D0; o1.z = C1; o1.w = D1;
            *(float4*)(w1 + 4*(ub + k) + 40*seg) = o1;
        }
    }
    __syncthreads();

    // ---- Phase D2: combine + coalesced float2 store; both channels ----
    float* ob0 = out + (size_t)bd0*HW;
    float* ob1 = ob0 + HW;
    for (int i = t; i < 2*TH*32; i += 512) {
        int u = i & 31, row = (i >> 5) & 31, ch = i >> 10;
        const float* Sx = ch ? S1 : S0;
        float* ox = ch ? ob1 : ob0;
        int prow = row + ((row >= 16) ? 10 : 0);
        int ww = 4*u + ((u >= 16) ? 40 : 0);
        float4 s4 = *(const float4*)(Sx + prow*PTW + ww);
        int gy = ty0 + row;
        int x0 = 2*u;
        float2 im2 = *(const float2*)(ib + gy*WW + tx0 + x0);
        float2 o;
        o.x = (s4.x*im2.x + s4.y)*inv121;
        o.y = (s4.z*im2.y + s4.w)*inv121;
        *(float2*)(ox + gy*WW + tx0 + x0) = o;
    }
}

extern "C" void kernel_launch(void* const* d_in, const int* in_sizes, int n_in,
                              void* d_out, int out_size, void* d_ws, size_t ws_size,
                              hipStream_t stream) {
    const float* feat = (const float*)d_in[0];
    const float* img  = (const float*)d_in[1];
    float* out  = (float*)d_out;
    float2* miv = (float2*)d_ws;             // NB*HW float2 = 16 MiB

    img_stats<<<NB*128, 256, 0, stream>>>(img, miv);
    guided_main<<<NB*(ND/2)*128, 512, 0, stream>>>(feat, img, miv, out);
}

// Round 19
// 144.679 us; speedup vs baseline: 1.1366x; 1.1366x over previous
//
#include <hip/hip_runtime.h>

#define HH 512
#define WW 512
#define HW (512*512)
#define NB 8
#define ND 16
#define TW 64            // tile width (output)
#define TH 64            // tile height (output)
#define VR 74            // v-sum rows = TH+10
#define PTW 172          // words/row: 84 cols x {F,P} + 4 pad; 172/4=43 odd ->
                         // row-lane b128 hits all 8 bank-quads bijectively

__device__ __forceinline__ int reflect(int v) {
    if (v < 0) v = -v;
    if (v >= HH) v = 2*HH - 2 - v;
    return v;
}

// ---------------- Prepass: {mean_I, 1/(var_I+eps)} interleaved float2 ----------------
__global__ __launch_bounds__(256) void img_stats(const float* __restrict__ img,
                                                 float2* __restrict__ miv) {
    const int VRs = 42, PTs = 86, THs = 32, TWs = 64;
    __shared__ __align__(16) float hBuf[2*VRs*PTs + 20];
    float* hF = hBuf;
    float* hP = hBuf + VRs*PTs + 20;

    int blk  = blockIdx.x;
    int tile = blk & 127;
    int b    = blk >> 7;
    int ty0  = (tile >> 3) * THs;
    int tx0  = (tile & 7)  * TWs;

    const float inv121 = 1.0f/121.0f;
    const float* ib = img + (size_t)b*HW;
    const int t = threadIdx.x;

    if (t < 252) {
        int seg = t / 84, col = t - seg*84;
        int gx = reflect(tx0 - 10 + col);
        const float* icol = ib + gx;
        int vr0 = seg*14;
        float rv[11], rq[11];
        float sv = 0.f, sq = 0.f;
        #pragma unroll
        for (int j = 0; j < 10; ++j) {
            int gy = reflect(ty0 - 10 + vr0 + j);
            float v = icol[gy*WW], q = v*v;
            rv[j] = v; rq[j] = q; sv += v; sq += q;
        }
        #pragma unroll
        for (int k = 0; k < 14; ++k) {
            int vr = vr0 + k;
            int gy = reflect(ty0 + vr);
            float v = icol[gy*WW], q = v*v;
            sv += v; sq += q;
            hF[vr*PTs + col] = sv;
            hP[vr*PTs + col] = sq;
            sv -= rv[k%11]; sq -= rq[k%11];
            rv[(k+10)%11] = v; rq[(k+10)%11] = q;
        }
    }
    __syncthreads();

    if (t < 168) {
        int arr = t & 1;
        int j2  = t >> 1;
        int seg = (j2 >= 42) ? 1 : 0;
        int vr  = j2 - seg*42;
        int xb = seg ? 38 : 0;
        int nout = seg ? 18 : 19;
        float* rA = (arr ? hP : hF) + vr*PTs;
        float2 ring[5];
        float T = 0.f;
        #pragma unroll
        for (int j = 0; j < 5; ++j) {
            float2 v = *(float2*)(rA + xb + 2*j);
            ring[j] = v; T += v.x + v.y;
        }
        #pragma unroll
        for (int k2 = 0; k2 < 19; ++k2) {
            if (k2 < nout) {
                int hc = xb + 2*k2;
                float2 p = *(float2*)(rA + hc + 10);
                float2 q = ring[k2 % 5];
                float O0 = T + p.x;
                float O1 = O0 + p.y - q.x;
                T = O1 - q.y;
                ring[k2 % 5] = p;
                float2 o; o.x = O0*inv121; o.y = O1*inv121;
                *(float2*)(rA + hc + 10*seg) = o;
            }
        }
    }
    __syncthreads();

    float2* mb = miv + (size_t)b*HW;
    for (int i = t; i < THs*TWs; i += 256) {
        int y = i >> 6, x = i & 63;
        int vr = y + 5, hc = x + 5;
        int slot = hc + ((hc >= 38) ? 10 : 0);
        float mI  = hF[vr*PTs + slot];
        float mII = hP[vr*PTs + slot];
        float var = mII - mI*mI;
        float2 o; o.x = mI; o.y = 1.0f / (var + 1e-8f);
        mb[(ty0 + y)*WW + tx0 + x] = o;
    }
}

// ---------------- Main fused kernel: one (b,d) channel, one 64x64 tile, 512 thr --------
// R16 structure; launch_bounds(512,6) matches the LDS-imposed 6 waves/EU so the
// compiler can use ~80 VGPRs; LDS prefetch deepened to 4 in B/C/D.
// Prefetch safety (depth 4): every prefetched unit/row is overwritten no earlier
// than 4 iterations after it is read (B seg1: read unit 28+k at iter k, written
// at k+4; C seg1: read row 46+k at k, written at k+4; D seg1: read su 30+k at k,
// written at k+4; all seg0 margins >= 9). Warm-up reads precede all in-loop writes.
__global__ __launch_bounds__(512, 6) void guided_main(const float* __restrict__ feat,
                                                      const float* __restrict__ img,
                                                      const float2* __restrict__ miv,
                                                      float* __restrict__ out) {
    __shared__ __align__(16) float S[VR*PTW];

    int blk  = blockIdx.x;
    int tile = blk & 63;         // 8 col-tiles x 8 row-tiles
    int bd   = blk >> 6;
    int b    = bd >> 4;
    int ty0  = (tile >> 3) * TH;
    int tx0  = (tile & 7)  * TW;

    const float inv121 = 1.0f/121.0f;
    const float* fb   = feat + (size_t)bd*HW;
    const float* ib   = img  + (size_t)b*HW;
    const float2* mivb = miv + (size_t)b*HW;
    const int t = threadIdx.x;

    // ---- Phase A: vertical raw 11-sums; one b64 {sf,sp} store (writes only) ----
    if (t < 504) {
        int seg = t / 84, col = t - seg*84;
        int gx = reflect(tx0 - 10 + col);
        const float* fcol = fb + gx;
        const float* icol = ib + gx;
        int vr0 = seg*13;
        float rf[11], rp[11];
        float sf = 0.f, sp = 0.f;
        #pragma unroll
        for (int j = 0; j < 10; ++j) {
            int gy = reflect(ty0 - 10 + vr0 + j);
            float f = fcol[gy*WW], im = icol[gy*WW];
            float p = f*im;
            rf[j] = f; rp[j] = p; sf += f; sp += p;
        }
        #pragma unroll
        for (int k = 0; k < 13; ++k) {
            int vr = vr0 + k;
            if (vr < VR) {
                int gy = reflect(ty0 + vr);
                float f = fcol[gy*WW], im = icol[gy*WW];
                float p = f*im;
                sf += f; sp += p;
                float2 st; st.x = sf; st.y = sp;
                *(float2*)(S + vr*PTW + 2*col) = st;
                sf -= rf[k%11]; sp -= rp[k%11];
                rf[(k+10)%11] = f; rp[(k+10)%11] = p;
            }
        }
    }
    __syncthreads();

    // ---- Phase B: horizontal 11-sums -> {mp,cip}; b128; prefetch-4 pipelined ----
    if (t < 148) {
        int seg = (t >= 74) ? 1 : 0;
        int vr  = t - seg*74;
        float* row = S + vr*PTW;
        int xbu = seg*19;
        int nout = seg ? 18 : 19;
        float4 ring[5];
        float TF = 0.f, TP = 0.f;
        #pragma unroll
        for (int j = 0; j < 5; ++j) {
            float4 v = *(float4*)(row + 4*(xbu + j));
            ring[j] = v; TF += v.x + v.z; TP += v.y + v.w;
        }
        float4 pre[4];
        #pragma unroll
        for (int j = 0; j < 4; ++j)
            pre[j] = *(float4*)(row + 4*(xbu + 5 + j));
        #pragma unroll
        for (int k = 0; k < 19; ++k) {
            if (k < nout) {
                float4 p = pre[k & 3];
                int nk = k + 4;
                if (nk < nout) pre[k & 3] = *(float4*)(row + 4*(xbu + 5 + nk));
                float4 q = ring[k % 5];
                float O0f = TF + p.x;
                float O1f = O0f + p.z - q.x;
                TF = O1f - q.z;
                float O0p = TP + p.y;
                float O1p = O0p + p.w - q.y;
                TP = O1p - q.w;
                ring[k % 5] = p;
                float4 o;
                o.x = O0f*inv121; o.y = O0p*inv121;
                o.z = O1f*inv121; o.w = O1p*inv121;
                *(float4*)(row + 4*(k + xbu + 5*seg)) = o;
            }
        }
    }
    __syncthreads();

    // ---- Phase B2: a,b elementwise; explicit next-job prefetch (LDS + miv) ----
    {
        const int NJ = VR*37;
        int i = t;
        float* cell = S;
        float4 mc = {};
        float2 g0 = {}, g1 = {};
        if (i < NJ) {
            int y = i / 37, u = i - y*37;
            int su = u + ((u >= 19) ? 5 : 0);
            cell = S + y*PTW + 4*su;
            mc = *(float4*)cell;
            int gy = reflect(ty0 - 5 + y);
            const float2* mrow = mivb + gy*WW;
            int gx0 = tx0 - 5 + 2*u;
            g0 = mrow[reflect(gx0)];
            g1 = mrow[reflect(gx0+1)];
        }
        while (i < NJ) {
            int inext = i + 512;
            float* celln = cell;
            float4 mcn = {};
            float2 g0n = {}, g1n = {};
            if (inext < NJ) {
                int yn = inext / 37, un = inext - yn*37;
                int sun = un + ((un >= 19) ? 5 : 0);
                celln = S + yn*PTW + 4*sun;
                mcn = *(float4*)celln;
                int gyn = reflect(ty0 - 5 + yn);
                const float2* mrown = mivb + gyn*WW;
                int gx0n = tx0 - 5 + 2*un;
                g0n = mrown[reflect(gx0n)];
                g1n = mrown[reflect(gx0n+1)];
            }
            float a0 = (mc.y - g0.x*mc.x) * g0.y;
            float b0 = mc.x - a0*g0.x;
            float a1 = (mc.w - g1.x*mc.z) * g1.y;
            float b1 = mc.z - a1*g1.x;
            float4 o; o.x = a0; o.y = b0; o.z = a1; o.w = b1;
            *(float4*)cell = o;
            i = inext; cell = celln; mc = mcn; g0 = g0n; g1 = g1n;
        }
    }
    __syncthreads();

    // ---- Phase C: vertical 11-sums of {a,b}; b64 per col; prefetch-4 pipelined ----
    if (t < 148) {
        int seg = (t >= 74) ? 1 : 0;
        int c   = t - seg*74;
        int sw  = 2*(c + ((c >= 38) ? 10 : 0));
        int y0  = seg*32;
        float2 ring[11];
        float sa = 0.f, sb = 0.f;
        #pragma unroll
        for (int j = 0; j < 10; ++j) {
            float2 v = *(float2*)(S + (y0+j)*PTW + sw);
            ring[j] = v; sa += v.x; sb += v.y;
        }
        float2 pre[4];
        #pragma unroll
        for (int j = 0; j < 4; ++j)
            pre[j] = *(float2*)(S + (y0+10+j)*PTW + sw);
        #pragma unroll
        for (int k = 0; k < 32; ++k) {
            float2 v = pre[k & 3];
            if (k + 4 < 32) pre[k & 3] = *(float2*)(S + (y0+14+k)*PTW + sw);
            sa += v.x; sb += v.y;
            int wrow = y0 + k + 10*seg;
            float2 o; o.x = sa; o.y = sb;
            *(float2*)(S + wrow*PTW + sw) = o;
            sa -= ring[k%11].x; sb -= ring[k%11].y;
            ring[(k+10)%11] = v;
        }
    }
    __syncthreads();

    // ---- Phase D: horizontal 11-sums of {sa,sb}; b128; prefetch-4 pipelined ----
    if (t < 128) {
        int seg = t >> 6, row = t & 63;
        int prow = row + ((row >= 32) ? 10 : 0);
        float* rw = S + prow*PTW;
        int ub = seg*16;
        float4 ring[5];
        float TA = 0.f, TB = 0.f;
        #pragma unroll
        for (int j = 0; j < 5; ++j) {
            int u = ub + j; int su = u + ((u >= 19) ? 5 : 0);
            float4 v = *(float4*)(rw + 4*su);
            ring[j] = v; TA += v.x + v.z; TB += v.y + v.w;
        }
        float4 pre[4];
        #pragma unroll
        for (int j = 0; j < 4; ++j) {
            int u = ub + 5 + j; int su = u + ((u >= 19) ? 5 : 0);
            pre[j] = *(float4*)(rw + 4*su);
        }
        #pragma unroll
        for (int k = 0; k < 16; ++k) {
            float4 p = pre[k & 3];
            if (k + 4 < 16) {
                int u = ub + 9 + k; int su = u + ((u >= 19) ? 5 : 0);
                pre[k & 3] = *(float4*)(rw + 4*su);
            }
            float4 q = ring[k % 5];
            float A0 = TA + p.x;
            float A1 = A0 + p.z - q.x;
            TA = A1 - q.z;
            float B0 = TB + p.y;
            float B1 = B0 + p.w - q.y;
            TB = B1 - q.w;
            ring[k % 5] = p;
            float4 o; o.x = A0; o.y = B0; o.z = A1; o.w = B1;
            *(float4*)(rw + 4*(ub + k) + 40*seg) = o;
        }
    }
    __syncthreads();

    // ---- Phase D2: combine + coalesced float2 store (read-only LDS) ----
    float* ob = out + (size_t)bd*HW;
    for (int i = t; i < TH*32; i += 512) {
        int row = i >> 5, u = i & 31;
        int prow = row + ((row >= 32) ? 10 : 0);
        int ww = 4*u + ((u >= 16) ? 40 : 0);
        float4 s4 = *(float4*)(S + prow*PTW + ww);
        int gy = ty0 + row;
        int x0 = 2*u;
        float2 im2 = *(const float2*)(ib + gy*WW + tx0 + x0);
        float2 o;
        o.x = (s4.x*im2.x + s4.y)*inv121;
        o.y = (s4.z*im2.y + s4.w)*inv121;
        *(float2*)(ob + gy*WW + tx0 + x0) = o;
    }
}

extern "C" void kernel_launch(void* const* d_in, const int* in_sizes, int n_in,
                              void* d_out, int out_size, void* d_ws, size_t ws_size,
                              hipStream_t stream) {
    const float* feat = (const float*)d_in[0];
    const float* img  = (const float*)d_in[1];
    float* out  = (float*)d_out;
    float2* miv = (float2*)d_ws;             // NB*HW float2 = 16 MiB

    img_stats<<<NB*128, 256, 0, stream>>>(img, miv);
    guided_main<<<NB*ND*64, 512, 0, stream>>>(feat, img, miv, out);
}